// Round 11
// baseline (157.809 us; speedup 1.0000x reference)
//
#include <hip/hip_runtime.h>

typedef _Float16 half_t;
typedef __attribute__((ext_vector_type(4))) _Float16 half4;   // 2 VGPRs
typedef __attribute__((ext_vector_type(8))) _Float16 half8;   // MFMA A/B frag (4 VGPRs)
typedef __attribute__((ext_vector_type(4))) float f32x4;      // MFMA C/D frag

#define NPOLY 16384   // B*N
#define PPTS  32
#define CIN   9
#define RSH   36      // fg row stride in halves (72B)

__device__ __forceinline__ half8 ld8(const half_t* p){
    return *reinterpret_cast<const half8*>(p);
}
__device__ __forceinline__ f32x4 MFMA(half8 a, half8 b, f32x4 c){
    return __builtin_amdgcn_mfma_f32_16x16x32_f16(a, b, c, 0, 0, 0);
}
// Merge own-parity halves of two row-dwords into one packed dword.
// lo = row j dword (points 2u,2u+1), hi = row j+1 dword; psel lane-const.
// v_perm_b32 pool: src1(lo)=bytes 0-3, src0(hi)=bytes 4-7.
// even: [lo0,lo1,hi0,hi1]=0x05040100; odd: [lo2,lo3,hi2,hi3]=0x07060302.
__device__ __forceinline__ unsigned PSEL(unsigned lo, unsigned hi, unsigned psel, unsigned sh){
#if __has_builtin(__builtin_amdgcn_perm)
    (void)sh;
    return __builtin_amdgcn_perm(hi, lo, psel);   // S0=hi(high pool), S1=lo(low pool)
#else
    return ((lo >> sh) & 0xffffu) | (((hi >> sh) & 0xffffu) << 16);
#endif
}

// =====================================================================
// LESSONS: (r1) d_ws re-poisoned each iter -> never read it.
// (r2/r5/r9) effective VGPR cap 128: batched frag builds or weight
// hoists spill (r9: VGPR=128, WRITE 8->17MB, dur 59). (r3) occupancy
// 12->16 waves/CU: no effect. (r4) rolled loop: best 43.6us. (r6)
// stagger/setprio: regression. (r7/r8) ds_read_b64_tr_b16: abandoned.
// (r9) [feat][point] layout VALIDATED: conflicts 589k->65k, passed.
// (r10) infra failure, kernel never ran -> resubmit.
// Pipe model (validated by MfmaUtil): DS ~57% of wall, VALU ~42%,
// MFMA ~13% -> DS-heaviest, sum-like behavior.
// THIS ROUND: r9 layout + register-lean reads: per-ks scoped frag
// builds (no af[2][2] batch) + v_perm_b32 1-op half-merge (was 5-op
// shift/mask). Stores stay 16 ds_write_b64/iter (was 64 b16 in r4).
// Block = 512 thr (8 waves) = 32 polylines; grid 512 = 2 blocks/CU.
// =====================================================================
__global__ __launch_bounds__(512, 2) void k_fused(
    const float* __restrict__ px,        // [NPOLY][32][9]
    const int*   __restrict__ pmask,     // [NPOLY][32]
    const float* __restrict__ w_pre, const float* __restrict__ b_pre,
    const float* __restrict__ g_pre, const float* __restrict__ be_pre,
    const float* __restrict__ rm_pre, const float* __restrict__ rv_pre,
    const float* __restrict__ w_m1, const float* __restrict__ b_m1,
    const float* __restrict__ g_m1, const float* __restrict__ be_m1,
    const float* __restrict__ rm_m1, const float* __restrict__ rv_m1,
    const float* __restrict__ w_m2, const float* __restrict__ b_m2,
    const float* __restrict__ g_m2, const float* __restrict__ be_m2,
    const float* __restrict__ rm_m2, const float* __restrict__ rv_m2,
    const float* __restrict__ w1, const float* __restrict__ b1,
    const float* __restrict__ w2, const float* __restrict__ b2,
    float* __restrict__ out)
{
    // encoder weight frags (f16, BN-scaled): pre 0..3, m1 4..19, m2 20..27
    __shared__ __align__(16) half_t lds_w[28 * 512];   // 28 KB
    __shared__ __align__(16) half_t fg[8][64 * RSH];   // 36 KB: [feat][point], 72B rows
    __shared__ __align__(16) half_t pooledb[8][64];    // 1 KB
    __shared__ __align__(16) half_t ft[32 * 72];       // 4.5 KB feat A-tile (32 rows)
    __shared__ __align__(16) half_t qt[32 * 72];       // 4.5 KB out1 A-tile
    __shared__ int maskb[8][2][32];                    // 2 KB (double-buffered)
    __shared__ int validb[32];

    const int tid  = threadIdx.x;
    const int wave = tid >> 6, lane = tid & 63, l15 = lane & 15, q = lane >> 4;

    // ---- stage encoder weights, fp32 -> f16, folding BN scale sA ----
    #pragma unroll 1
    for (int s = tid; s < 28 * 64; s += 512) {
        int frag = s >> 6, ln = s & 63;
        const float *W, *G, *RV; int K, ks, nt;
        if (frag < 4)       { W = w_pre; G = g_pre; RV = rv_pre; K = CIN; ks = 0; nt = frag; }
        else if (frag < 20) { W = w_m1;  G = g_m1;  RV = rv_m1;  K = 128; int f = frag - 4;  ks = f >> 2; nt = f & 3; }
        else                { W = w_m2;  G = g_m2;  RV = rv_m2;  K = 64;  int f = frag - 20; ks = f >> 2; nt = f & 3; }
        int col = nt * 16 + (ln & 15);
        int kb  = ks * 32 + ((ln >> 4) << 3);
        float sA = G[col] * rsqrtf(RV[col] + 1e-5f);
        half_t* dst = &lds_w[s * 8];
        #pragma unroll
        for (int j = 0; j < 8; j++) {
            int k  = kb + j;
            int ka = (k < K) ? k : 0;
            float v = W[ka * 64 + col] * sA;
            dst[j] = (k < K) ? (half_t)v : (half_t)0.f;
        }
    }

    // ---- per-lane BN bias consts (go into MFMA acc init), h = nt*16+l15 ----
    float sC0[4], sC1[4], sC2[4];
    #pragma unroll
    for (int nt = 0; nt < 4; nt++) {
        int h = nt * 16 + l15; float a;
        a = g_pre[h] * rsqrtf(rv_pre[h] + 1e-5f); sC0[nt] = (b_pre[h] - rm_pre[h]) * a + be_pre[h];
        a = g_m1[h]  * rsqrtf(rv_m1[h]  + 1e-5f); sC1[nt] = (b_m1[h]  - rm_m1[h])  * a + be_m1[h];
        a = g_m2[h]  * rsqrtf(rv_m2[h]  + 1e-5f); sC2[nt] = (b_m2[h]  - rm_m2[h])  * a + be_m2[h];
    }

    const int nbase = blockIdx.x * 32 + wave * 4;

    // ---- fg bases ----
    // store: value(pt=4q+r+16mt, feat=16nt+l15) at halves
    //   (16nt+l15)*RSH + 4q + 16mt  ->  base l15*RSH + q*4, imm nt*16*RSH + mt*16
    half_t* const fgw   = &fg[wave][0];
    half_t* const fg_st = fgw + l15 * RSH + q * 4;
    // read: feat=32ks+8q+j row, point-pair dword containing l15 (+16mt):
    //   byte = (32ks+8q+j)*72 + (l15>>1)*4 + mt*32 -> base q*576 + (l15>>1)*4
    const char* const fg_rb = (const char*)fgw + q * 576 + (l15 >> 1) * 4;
    const unsigned sh   = (unsigned)((l15 & 1) * 16);
    const unsigned psel = (l15 & 1) ? 0x07060302u : 0x05040100u;
    const half_t* const lwb = lds_w + lane * 8;
    half_t* const pbw = &pooledb[wave][0];

    // ---- prefetch iter 0 x (lanes q<2) and mask (lanes 32..63) ----
    float xr[2][8];
    #pragma unroll
    for (int mt = 0; mt < 2; mt++) {
        const float* src = px + ((long)nbase * PPTS + l15 + 16 * mt) * CIN;
        if (q == 0) {
            #pragma unroll
            for (int j = 0; j < 8; j++) xr[mt][j] = src[j];
        } else if (q == 1) {
            xr[mt][0] = src[8];
        }
    }
    if (lane >= 32) maskb[wave][0][lane - 32] = pmask[nbase * PPTS + (lane - 32)];

    __syncthreads();   // weights staged

    // pre-layer B-frags reused every iteration: hoist to registers
    half8 preb[4];
    #pragma unroll
    for (int nt = 0; nt < 4; nt++) preb[nt] = ld8(lwb + nt * 512);

    // ---- main loop: rolled (r4 lesson) ----
    #pragma unroll 1
    for (int it = 0; it < 4; ++it) {
        const int n = nbase + it;

        // ---- issue next-iteration prefetch loads ----
        float xn[2][8]; int mnext = 0;
        if (it < 3) {
            #pragma unroll
            for (int mt = 0; mt < 2; mt++) {
                const float* src = px + ((long)(n + 1) * PPTS + l15 + 16 * mt) * CIN;
                if (q == 0) {
                    #pragma unroll
                    for (int j = 0; j < 8; j++) xn[mt][j] = src[j];
                } else if (q == 1) {
                    xn[mt][0] = src[8];
                }
            }
            if (lane >= 32) mnext = pmask[(n + 1) * PPTS + (lane - 32)];
        }

        // ---- build x A-frags (K=9 zero-padded to 32) ----
        half8 xa[2];
        #pragma unroll
        for (int mt = 0; mt < 2; mt++) {
            half8 v;
            #pragma unroll
            for (int j = 0; j < 8; j++) v[j] = (half_t)0.f;
            if (q == 0) {
                #pragma unroll
                for (int j = 0; j < 8; j++) v[j] = (half_t)xr[mt][j];
            } else if (q == 1) {
                v[0] = (half_t)xr[mt][0];
            }
            xa[mt] = v;
        }

        // ---- pre layer: acc init = sC0 (BN bias) ----
        f32x4 acc[2][4];
        #pragma unroll
        for (int mt = 0; mt < 2; mt++)
            #pragma unroll
            for (int nt = 0; nt < 4; nt++)
                #pragma unroll
                for (int r = 0; r < 4; r++) acc[mt][nt][r] = sC0[nt];

        #pragma unroll
        for (int nt = 0; nt < 4; nt++) {
            acc[0][nt] = MFMA(xa[0], preb[nt], acc[0][nt]);
            acc[1][nt] = MFMA(xa[1], preb[nt], acc[1][nt]);
        }

        float maskf[8];
        #pragma unroll
        for (int mt = 0; mt < 2; mt++)
            #pragma unroll
            for (int r = 0; r < 4; r++)
                maskf[mt * 4 + r] = maskb[wave][it & 1][mt * 16 + q * 4 + r] ? 1.f : 0.f;

        // ReLU+mask -> packed half4 [feat][point] stores; track pooled max
        float pm[4];
        #pragma unroll
        for (int nt = 0; nt < 4; nt++) {
            float m = 0.f;
            #pragma unroll
            for (int mt = 0; mt < 2; mt++) {
                float v0 = fmaxf(acc[mt][nt][0], 0.f) * maskf[mt * 4 + 0];
                float v1 = fmaxf(acc[mt][nt][1], 0.f) * maskf[mt * 4 + 1];
                float v2 = fmaxf(acc[mt][nt][2], 0.f) * maskf[mt * 4 + 2];
                float v3 = fmaxf(acc[mt][nt][3], 0.f) * maskf[mt * 4 + 3];
                half4 h; h[0] = (half_t)v0; h[1] = (half_t)v1; h[2] = (half_t)v2; h[3] = (half_t)v3;
                *reinterpret_cast<half4*>(fg_st + nt * (16 * RSH) + mt * 16) = h;
                m = fmaxf(m, fmaxf(fmaxf(v0, v1), fmaxf(v2, v3)));
            }
            m = fmaxf(m, __shfl_xor(m, 16));
            m = fmaxf(m, __shfl_xor(m, 32));
            pm[nt] = m;
        }
        {
            float pv = (q == 0) ? pm[0] : (q == 1) ? pm[1] : (q == 2) ? pm[2] : pm[3];
            pbw[lane] = (half_t)pv;   // col = q*16+l15 = lane
        }

        // ---- l1: A = [f | pooled-bcast] (32x128) @ (128x64), init sC1 ----
        f32x4 acc1[2][4];
        #pragma unroll
        for (int mt = 0; mt < 2; mt++)
            #pragma unroll
            for (int nt = 0; nt < 4; nt++)
                #pragma unroll
                for (int r = 0; r < 4; r++) acc1[mt][nt][r] = sC1[nt];

        half8 pa0 = ld8(pbw + q * 8);
        half8 pa1 = ld8(pbw + 32 + q * 8);

        // f-part: per-ks scoped frag build (register-lean) + MFMA
        #pragma unroll
        for (int ks = 0; ks < 2; ks++) {
            half8 a0, a1;
            {
                const char* rb = fg_rb + ks * 2304;
                union { unsigned u[4]; half8 h; } cv;
                #pragma unroll
                for (int t = 0; t < 4; t++) {
                    unsigned lo = *(const unsigned*)(rb + (2 * t) * 72);
                    unsigned hi = *(const unsigned*)(rb + (2 * t + 1) * 72);
                    cv.u[t] = PSEL(lo, hi, psel, sh);
                }
                a0 = cv.h;
                #pragma unroll
                for (int t = 0; t < 4; t++) {
                    unsigned lo = *(const unsigned*)(rb + (2 * t) * 72 + 32);
                    unsigned hi = *(const unsigned*)(rb + (2 * t + 1) * 72 + 32);
                    cv.u[t] = PSEL(lo, hi, psel, sh);
                }
                a1 = cv.h;
            }
            #pragma unroll
            for (int nt = 0; nt < 4; nt++) {
                half8 b = ld8(lwb + (4 + ks * 4 + nt) * 512);
                acc1[0][nt] = MFMA(a0, b, acc1[0][nt]);
                acc1[1][nt] = MFMA(a1, b, acc1[1][nt]);
            }
        }
        #pragma unroll
        for (int ks = 2; ks < 4; ks++) {
            half8 ap = (ks == 2) ? pa0 : pa1;
            #pragma unroll
            for (int nt = 0; nt < 4; nt++) {
                half8 b = ld8(lwb + (4 + ks * 4 + nt) * 512);
                acc1[0][nt] = MFMA(ap, b, acc1[0][nt]);
                acc1[1][nt] = MFMA(ap, b, acc1[1][nt]);
            }
        }

        // ReLU only -> packed stores (overwrite f with g)
        #pragma unroll
        for (int nt = 0; nt < 4; nt++)
            #pragma unroll
            for (int mt = 0; mt < 2; mt++) {
                half4 h;
                h[0] = (half_t)fmaxf(acc1[mt][nt][0], 0.f);
                h[1] = (half_t)fmaxf(acc1[mt][nt][1], 0.f);
                h[2] = (half_t)fmaxf(acc1[mt][nt][2], 0.f);
                h[3] = (half_t)fmaxf(acc1[mt][nt][3], 0.f);
                *reinterpret_cast<half4*>(fg_st + nt * (16 * RSH) + mt * 16) = h;
            }

        // ---- l2: (32x64) @ (64x64), init sC2 ----
        f32x4 acc2[2][4];
        #pragma unroll
        for (int mt = 0; mt < 2; mt++)
            #pragma unroll
            for (int nt = 0; nt < 4; nt++)
                #pragma unroll
                for (int r = 0; r < 4; r++) acc2[mt][nt][r] = sC2[nt];

        #pragma unroll
        for (int ks = 0; ks < 2; ks++) {
            half8 a0, a1;
            {
                const char* rb = fg_rb + ks * 2304;
                union { unsigned u[4]; half8 h; } cv;
                #pragma unroll
                for (int t = 0; t < 4; t++) {
                    unsigned lo = *(const unsigned*)(rb + (2 * t) * 72);
                    unsigned hi = *(const unsigned*)(rb + (2 * t + 1) * 72);
                    cv.u[t] = PSEL(lo, hi, psel, sh);
                }
                a0 = cv.h;
                #pragma unroll
                for (int t = 0; t < 4; t++) {
                    unsigned lo = *(const unsigned*)(rb + (2 * t) * 72 + 32);
                    unsigned hi = *(const unsigned*)(rb + (2 * t + 1) * 72 + 32);
                    cv.u[t] = PSEL(lo, hi, psel, sh);
                }
                a1 = cv.h;
            }
            #pragma unroll
            for (int nt = 0; nt < 4; nt++) {
                half8 b = ld8(lwb + (20 + ks * 4 + nt) * 512);
                acc2[0][nt] = MFMA(a0, b, acc2[0][nt]);
                acc2[1][nt] = MFMA(a1, b, acc2[1][nt]);
            }
        }

        // ReLU+mask, masked max over points -> feat row into ft tile
        float fm[4];
        #pragma unroll
        for (int nt = 0; nt < 4; nt++) {
            float m = 0.f;
            #pragma unroll
            for (int mt = 0; mt < 2; mt++)
                #pragma unroll
                for (int r = 0; r < 4; r++) {
                    float v = fmaxf(acc2[mt][nt][r], 0.f) * maskf[mt * 4 + r];
                    m = fmaxf(m, v);
                }
            m = fmaxf(m, __shfl_xor(m, 16));
            m = fmaxf(m, __shfl_xor(m, 32));
            fm[nt] = m;
        }
        float fv = (q == 0) ? fm[0] : (q == 1) ? fm[1] : (q == 2) ? fm[2] : fm[3];
        ft[(wave * 4 + it) * 72 + lane] = (half_t)fv;   // row = 4w+it, col = lane

        int lm = 0;
        #pragma unroll
        for (int j = 0; j < 8; j++) lm |= (maskf[j] != 0.f);
        unsigned long long bal = __ballot(lm);
        if (lane == 0) validb[wave * 4 + it] = bal ? 1 : 0;

        // ---- commit prefetch for next iteration ----
        if (it < 3) {
            if (lane >= 32) maskb[wave][(it + 1) & 1][lane - 32] = mnext;
            #pragma unroll
            for (int mt = 0; mt < 2; mt++)
                #pragma unroll
                for (int j = 0; j < 8; j++) xr[mt][j] = xn[mt][j];
        }
    }

    // =============== out-MLP stage (M=32 rows per block) ===============
    // 8 waves <-> 8 tiles: wave w owns (mt_o = w>>2, nt1 = w&3) for out1,
    // cols nt1 and nt1+4 for out2. B-frags straight from global (L2).
    const int mt_o = wave >> 2, nt1 = wave & 3;
    float bb1 = b1[nt1 * 16 + l15];
    half8 bw1[2];
    #pragma unroll
    for (int ks = 0; ks < 2; ks++)
        #pragma unroll
        for (int j = 0; j < 8; j++)
            bw1[ks][j] = (half_t)w1[(ks * 32 + q * 8 + j) * 64 + nt1 * 16 + l15];

    float bb2[2];
    half8 bw2[2][2];   // [ks][t]
    #pragma unroll
    for (int t = 0; t < 2; t++) {
        int c = (nt1 + 4 * t) * 16 + l15;
        bb2[t] = b2[c];
        #pragma unroll
        for (int ks = 0; ks < 2; ks++)
            #pragma unroll
            for (int j = 0; j < 8; j++)
                bw2[ks][t][j] = (half_t)w2[(ks * 32 + q * 8 + j) * 128 + c];
    }

    __syncthreads();   // ft + validb complete

    // out1: wave w computes rows mt_o*16.., cols nt1*16..
    f32x4 o1;
    #pragma unroll
    for (int r = 0; r < 4; r++) o1[r] = bb1;
    #pragma unroll
    for (int ks = 0; ks < 2; ks++) {
        half8 a = ld8(&ft[(mt_o * 16 + l15) * 72 + ks * 32 + q * 8]);
        o1 = MFMA(a, bw1[ks], o1);
    }
    #pragma unroll
    for (int r = 0; r < 4; r++) {
        float v = fmaxf(o1[r], 0.f);
        qt[(mt_o * 16 + q * 4 + r) * 72 + nt1 * 16 + l15] = (half_t)v;
    }

    __syncthreads();   // qt complete

    // out2: wave w computes rows mt_o*16.., cols nt1*16 and (nt1+4)*16
    f32x4 o2[2];
    #pragma unroll
    for (int t = 0; t < 2; t++)
        #pragma unroll
        for (int r = 0; r < 4; r++) o2[t][r] = bb2[t];
    #pragma unroll
    for (int ks = 0; ks < 2; ks++) {
        half8 a = ld8(&qt[(mt_o * 16 + l15) * 72 + ks * 32 + q * 8]);
        o2[0] = MFMA(a, bw2[ks][0], o2[0]);
        o2[1] = MFMA(a, bw2[ks][1], o2[1]);
    }
    #pragma unroll
    for (int r = 0; r < 4; r++) {
        int row = mt_o * 16 + q * 4 + r;
        float vr = validb[row] ? 1.f : 0.f;
        long rowg = (long)(blockIdx.x * 32 + row);
        out[rowg * 128 + (nt1 + 0) * 16 + l15] = o2[0][r] * vr;
        out[rowg * 128 + (nt1 + 4) * 16 + l15] = o2[1][r] * vr;
    }
}

extern "C" void kernel_launch(void* const* d_in, const int* in_sizes, int n_in,
                              void* d_out, int out_size, void* d_ws, size_t ws_size,
                              hipStream_t stream) {
    (void)in_sizes; (void)n_in; (void)out_size; (void)d_ws; (void)ws_size;
    k_fused<<<dim3(NPOLY / 32), dim3(512), 0, stream>>>(
        (const float*)d_in[0], (const int*)d_in[1],
        (const float*)d_in[2],  (const float*)d_in[3],  (const float*)d_in[4],
        (const float*)d_in[5],  (const float*)d_in[6],  (const float*)d_in[7],
        (const float*)d_in[8],  (const float*)d_in[9],  (const float*)d_in[10],
        (const float*)d_in[11], (const float*)d_in[12], (const float*)d_in[13],
        (const float*)d_in[14], (const float*)d_in[15], (const float*)d_in[16],
        (const float*)d_in[17], (const float*)d_in[18], (const float*)d_in[19],
        (const float*)d_in[20], (const float*)d_in[21],
        (const float*)d_in[22], (const float*)d_in[23],
        (float*)d_out);
}

// Round 12
// 154.676 us; speedup vs baseline: 1.0203x; 1.0203x over previous
//
#include <hip/hip_runtime.h>

typedef _Float16 half_t;
typedef __attribute__((ext_vector_type(4))) _Float16 half4;   // 2 VGPRs
typedef __attribute__((ext_vector_type(8))) _Float16 half8;   // MFMA A/B frag (4 VGPRs)
typedef __attribute__((ext_vector_type(4))) float f32x4;      // MFMA C/D frag

#define NPOLY 16384   // B*N
#define PPTS  32
#define CIN   9
#define RSH   36      // fg row stride in halves (72B)

__device__ __forceinline__ half8 ld8(const half_t* p){
    return *reinterpret_cast<const half8*>(p);
}
__device__ __forceinline__ f32x4 MFMA(half8 a, half8 b, f32x4 c){
    return __builtin_amdgcn_mfma_f32_16x16x32_f16(a, b, c, 0, 0, 0);
}
// Merge own-parity halves of two row-dwords into one packed dword.
// v_perm_b32 pool: src1(lo)=bytes 0-3, src0(hi)=bytes 4-7.
// even: [lo0,lo1,hi0,hi1]=0x05040100; odd: [lo2,lo3,hi2,hi3]=0x07060302.
__device__ __forceinline__ unsigned PSEL(unsigned lo, unsigned hi, unsigned psel, unsigned sh){
#if __has_builtin(__builtin_amdgcn_perm)
    (void)sh;
    return __builtin_amdgcn_perm(hi, lo, psel);   // S0=hi(high pool), S1=lo(low pool)
#else
    return ((lo >> sh) & 0xffffu) | (((hi >> sh) & 0xffffu) << 16);
#endif
}

// =====================================================================
// LESSONS: (r1) d_ws re-poisoned each iter -> never read it.
// (r2/r5/r9/r11) VGPR cap 128 at this shape; any variant whose peak
// live state exceeds it spills (r9: WRITE 8->17MB; r11: 8->25MB).
// (r3) occupancy 12->16 waves/CU: no effect. (r4) rolled loop: best
// 43.6us. (r6) stagger/setprio: regression. (r7/r8) tr_b16: abandoned.
// (r9/r11) [feat][point] packed-store layout VALIDATED (conflicts
// 589k->65k, correct) but read path spilled: 32 f32 prefetch regs
// (xr+xn) live across the whole iteration were the avoidable cost.
// THIS ROUND: r11 + prefetch register relief. x converts to half8 xa
// immediately (iter-0 in prologue); in-loop prefetch issues late
// (after l1 MFMA) and converts at iter end -> f32 temps live ~40% of
// iter. Peak live ~107 regs < 128 -> no spill.
// Block = 512 thr (8 waves) = 32 polylines; grid 512 = 2 blocks/CU.
// =====================================================================
__global__ __launch_bounds__(512, 2) void k_fused(
    const float* __restrict__ px,        // [NPOLY][32][9]
    const int*   __restrict__ pmask,     // [NPOLY][32]
    const float* __restrict__ w_pre, const float* __restrict__ b_pre,
    const float* __restrict__ g_pre, const float* __restrict__ be_pre,
    const float* __restrict__ rm_pre, const float* __restrict__ rv_pre,
    const float* __restrict__ w_m1, const float* __restrict__ b_m1,
    const float* __restrict__ g_m1, const float* __restrict__ be_m1,
    const float* __restrict__ rm_m1, const float* __restrict__ rv_m1,
    const float* __restrict__ w_m2, const float* __restrict__ b_m2,
    const float* __restrict__ g_m2, const float* __restrict__ be_m2,
    const float* __restrict__ rm_m2, const float* __restrict__ rv_m2,
    const float* __restrict__ w1, const float* __restrict__ b1,
    const float* __restrict__ w2, const float* __restrict__ b2,
    float* __restrict__ out)
{
    // encoder weight frags (f16, BN-scaled): pre 0..3, m1 4..19, m2 20..27
    __shared__ __align__(16) half_t lds_w[28 * 512];   // 28 KB
    __shared__ __align__(16) half_t fg[8][64 * RSH];   // 36 KB: [feat][point], 72B rows
    __shared__ __align__(16) half_t pooledb[8][64];    // 1 KB
    __shared__ __align__(16) half_t ft[32 * 72];       // 4.5 KB feat A-tile (32 rows)
    __shared__ __align__(16) half_t qt[32 * 72];       // 4.5 KB out1 A-tile
    __shared__ int maskb[8][2][32];                    // 2 KB (double-buffered)
    __shared__ int validb[32];

    const int tid  = threadIdx.x;
    const int wave = tid >> 6, lane = tid & 63, l15 = lane & 15, q = lane >> 4;

    // ---- stage encoder weights, fp32 -> f16, folding BN scale sA ----
    #pragma unroll 1
    for (int s = tid; s < 28 * 64; s += 512) {
        int frag = s >> 6, ln = s & 63;
        const float *W, *G, *RV; int K, ks, nt;
        if (frag < 4)       { W = w_pre; G = g_pre; RV = rv_pre; K = CIN; ks = 0; nt = frag; }
        else if (frag < 20) { W = w_m1;  G = g_m1;  RV = rv_m1;  K = 128; int f = frag - 4;  ks = f >> 2; nt = f & 3; }
        else                { W = w_m2;  G = g_m2;  RV = rv_m2;  K = 64;  int f = frag - 20; ks = f >> 2; nt = f & 3; }
        int col = nt * 16 + (ln & 15);
        int kb  = ks * 32 + ((ln >> 4) << 3);
        float sA = G[col] * rsqrtf(RV[col] + 1e-5f);
        half_t* dst = &lds_w[s * 8];
        #pragma unroll
        for (int j = 0; j < 8; j++) {
            int k  = kb + j;
            int ka = (k < K) ? k : 0;
            float v = W[ka * 64 + col] * sA;
            dst[j] = (k < K) ? (half_t)v : (half_t)0.f;
        }
    }

    // ---- per-lane BN bias consts (go into MFMA acc init), h = nt*16+l15 ----
    float sC0[4], sC1[4], sC2[4];
    #pragma unroll
    for (int nt = 0; nt < 4; nt++) {
        int h = nt * 16 + l15; float a;
        a = g_pre[h] * rsqrtf(rv_pre[h] + 1e-5f); sC0[nt] = (b_pre[h] - rm_pre[h]) * a + be_pre[h];
        a = g_m1[h]  * rsqrtf(rv_m1[h]  + 1e-5f); sC1[nt] = (b_m1[h]  - rm_m1[h])  * a + be_m1[h];
        a = g_m2[h]  * rsqrtf(rv_m2[h]  + 1e-5f); sC2[nt] = (b_m2[h]  - rm_m2[h])  * a + be_m2[h];
    }

    const int nbase = blockIdx.x * 32 + wave * 4;

    // ---- fg bases ----
    // store: value(pt=4q+r+16mt, feat=16nt+l15) at halves
    //   (16nt+l15)*RSH + 4q + 16mt  ->  base l15*RSH + q*4, imm nt*16*RSH + mt*16
    half_t* const fgw   = &fg[wave][0];
    half_t* const fg_st = fgw + l15 * RSH + q * 4;
    // read: feat=32ks+8q+j row, point-pair dword containing l15 (+16mt):
    //   byte = (32ks+8q+j)*72 + (l15>>1)*4 + mt*32 -> base q*576 + (l15>>1)*4
    const char* const fg_rb = (const char*)fgw + q * 576 + (l15 >> 1) * 4;
    const unsigned sh   = (unsigned)((l15 & 1) * 16);
    const unsigned psel = (l15 & 1) ? 0x07060302u : 0x05040100u;
    const half_t* const lwb = lds_w + lane * 8;
    half_t* const pbw = &pooledb[wave][0];

    // ---- iter-0 x: load AND convert immediately (f32 temps die here) ----
    half8 xa[2];
    {
        float x0[2][8];
        #pragma unroll
        for (int mt = 0; mt < 2; mt++) {
            const float* src = px + ((long)nbase * PPTS + l15 + 16 * mt) * CIN;
            if (q == 0) {
                #pragma unroll
                for (int j = 0; j < 8; j++) x0[mt][j] = src[j];
            } else if (q == 1) {
                x0[mt][0] = src[8];
            }
        }
        #pragma unroll
        for (int mt = 0; mt < 2; mt++) {
            half8 v;
            #pragma unroll
            for (int j = 0; j < 8; j++) v[j] = (half_t)0.f;
            if (q == 0) {
                #pragma unroll
                for (int j = 0; j < 8; j++) v[j] = (half_t)x0[mt][j];
            } else if (q == 1) {
                v[0] = (half_t)x0[mt][0];
            }
            xa[mt] = v;
        }
    }
    if (lane >= 32) maskb[wave][0][lane - 32] = pmask[nbase * PPTS + (lane - 32)];

    __syncthreads();   // weights staged

    // pre-layer B-frags reused every iteration: hoist to registers
    half8 preb[4];
    #pragma unroll
    for (int nt = 0; nt < 4; nt++) preb[nt] = ld8(lwb + nt * 512);

    // ---- main loop: rolled (r4 lesson) ----
    #pragma unroll 1
    for (int it = 0; it < 4; ++it) {
        const int n = nbase + it;

        // ---- pre layer: acc init = sC0 (BN bias) ----
        f32x4 acc[2][4];
        #pragma unroll
        for (int mt = 0; mt < 2; mt++)
            #pragma unroll
            for (int nt = 0; nt < 4; nt++)
                #pragma unroll
                for (int r = 0; r < 4; r++) acc[mt][nt][r] = sC0[nt];

        #pragma unroll
        for (int nt = 0; nt < 4; nt++) {
            acc[0][nt] = MFMA(xa[0], preb[nt], acc[0][nt]);
            acc[1][nt] = MFMA(xa[1], preb[nt], acc[1][nt]);
        }

        float maskf[8];
        #pragma unroll
        for (int mt = 0; mt < 2; mt++)
            #pragma unroll
            for (int r = 0; r < 4; r++)
                maskf[mt * 4 + r] = maskb[wave][it & 1][mt * 16 + q * 4 + r] ? 1.f : 0.f;

        // ReLU+mask -> packed half4 [feat][point] stores; track pooled max
        float pm[4];
        #pragma unroll
        for (int nt = 0; nt < 4; nt++) {
            float m = 0.f;
            #pragma unroll
            for (int mt = 0; mt < 2; mt++) {
                float v0 = fmaxf(acc[mt][nt][0], 0.f) * maskf[mt * 4 + 0];
                float v1 = fmaxf(acc[mt][nt][1], 0.f) * maskf[mt * 4 + 1];
                float v2 = fmaxf(acc[mt][nt][2], 0.f) * maskf[mt * 4 + 2];
                float v3 = fmaxf(acc[mt][nt][3], 0.f) * maskf[mt * 4 + 3];
                half4 h; h[0] = (half_t)v0; h[1] = (half_t)v1; h[2] = (half_t)v2; h[3] = (half_t)v3;
                *reinterpret_cast<half4*>(fg_st + nt * (16 * RSH) + mt * 16) = h;
                m = fmaxf(m, fmaxf(fmaxf(v0, v1), fmaxf(v2, v3)));
            }
            m = fmaxf(m, __shfl_xor(m, 16));
            m = fmaxf(m, __shfl_xor(m, 32));
            pm[nt] = m;
        }
        {
            float pv = (q == 0) ? pm[0] : (q == 1) ? pm[1] : (q == 2) ? pm[2] : pm[3];
            pbw[lane] = (half_t)pv;   // col = q*16+l15 = lane
        }

        // ---- l1: A = [f | pooled-bcast] (32x128) @ (128x64), init sC1 ----
        f32x4 acc1[2][4];
        #pragma unroll
        for (int mt = 0; mt < 2; mt++)
            #pragma unroll
            for (int nt = 0; nt < 4; nt++)
                #pragma unroll
                for (int r = 0; r < 4; r++) acc1[mt][nt][r] = sC1[nt];

        half8 pa0 = ld8(pbw + q * 8);
        half8 pa1 = ld8(pbw + 32 + q * 8);

        // f-part: per-ks scoped frag build + MFMA
        #pragma unroll
        for (int ks = 0; ks < 2; ks++) {
            half8 a0, a1;
            {
                const char* rb = fg_rb + ks * 2304;
                union { unsigned u[4]; half8 h; } cv;
                #pragma unroll
                for (int t = 0; t < 4; t++) {
                    unsigned lo = *(const unsigned*)(rb + (2 * t) * 72);
                    unsigned hi = *(const unsigned*)(rb + (2 * t + 1) * 72);
                    cv.u[t] = PSEL(lo, hi, psel, sh);
                }
                a0 = cv.h;
                #pragma unroll
                for (int t = 0; t < 4; t++) {
                    unsigned lo = *(const unsigned*)(rb + (2 * t) * 72 + 32);
                    unsigned hi = *(const unsigned*)(rb + (2 * t + 1) * 72 + 32);
                    cv.u[t] = PSEL(lo, hi, psel, sh);
                }
                a1 = cv.h;
            }
            #pragma unroll
            for (int nt = 0; nt < 4; nt++) {
                half8 b = ld8(lwb + (4 + ks * 4 + nt) * 512);
                acc1[0][nt] = MFMA(a0, b, acc1[0][nt]);
                acc1[1][nt] = MFMA(a1, b, acc1[1][nt]);
            }
        }
        #pragma unroll
        for (int ks = 2; ks < 4; ks++) {
            half8 ap = (ks == 2) ? pa0 : pa1;
            #pragma unroll
            for (int nt = 0; nt < 4; nt++) {
                half8 b = ld8(lwb + (4 + ks * 4 + nt) * 512);
                acc1[0][nt] = MFMA(ap, b, acc1[0][nt]);
                acc1[1][nt] = MFMA(ap, b, acc1[1][nt]);
            }
        }

        // ---- issue next-iter prefetch LATE (covers ~40% of iter) ----
        float xn[2][8]; int mnext = 0;
        if (it < 3) {
            #pragma unroll
            for (int mt = 0; mt < 2; mt++) {
                const float* src = px + ((long)(n + 1) * PPTS + l15 + 16 * mt) * CIN;
                if (q == 0) {
                    #pragma unroll
                    for (int j = 0; j < 8; j++) xn[mt][j] = src[j];
                } else if (q == 1) {
                    xn[mt][0] = src[8];
                }
            }
            if (lane >= 32) mnext = pmask[(n + 1) * PPTS + (lane - 32)];
        }

        // ReLU only -> packed stores (overwrite f with g)
        #pragma unroll
        for (int nt = 0; nt < 4; nt++)
            #pragma unroll
            for (int mt = 0; mt < 2; mt++) {
                half4 h;
                h[0] = (half_t)fmaxf(acc1[mt][nt][0], 0.f);
                h[1] = (half_t)fmaxf(acc1[mt][nt][1], 0.f);
                h[2] = (half_t)fmaxf(acc1[mt][nt][2], 0.f);
                h[3] = (half_t)fmaxf(acc1[mt][nt][3], 0.f);
                *reinterpret_cast<half4*>(fg_st + nt * (16 * RSH) + mt * 16) = h;
            }

        // ---- l2: (32x64) @ (64x64), init sC2 ----
        f32x4 acc2[2][4];
        #pragma unroll
        for (int mt = 0; mt < 2; mt++)
            #pragma unroll
            for (int nt = 0; nt < 4; nt++)
                #pragma unroll
                for (int r = 0; r < 4; r++) acc2[mt][nt][r] = sC2[nt];

        #pragma unroll
        for (int ks = 0; ks < 2; ks++) {
            half8 a0, a1;
            {
                const char* rb = fg_rb + ks * 2304;
                union { unsigned u[4]; half8 h; } cv;
                #pragma unroll
                for (int t = 0; t < 4; t++) {
                    unsigned lo = *(const unsigned*)(rb + (2 * t) * 72);
                    unsigned hi = *(const unsigned*)(rb + (2 * t + 1) * 72);
                    cv.u[t] = PSEL(lo, hi, psel, sh);
                }
                a0 = cv.h;
                #pragma unroll
                for (int t = 0; t < 4; t++) {
                    unsigned lo = *(const unsigned*)(rb + (2 * t) * 72 + 32);
                    unsigned hi = *(const unsigned*)(rb + (2 * t + 1) * 72 + 32);
                    cv.u[t] = PSEL(lo, hi, psel, sh);
                }
                a1 = cv.h;
            }
            #pragma unroll
            for (int nt = 0; nt < 4; nt++) {
                half8 b = ld8(lwb + (20 + ks * 4 + nt) * 512);
                acc2[0][nt] = MFMA(a0, b, acc2[0][nt]);
                acc2[1][nt] = MFMA(a1, b, acc2[1][nt]);
            }
        }

        // ReLU+mask, masked max over points -> feat row into ft tile
        float fm[4];
        #pragma unroll
        for (int nt = 0; nt < 4; nt++) {
            float m = 0.f;
            #pragma unroll
            for (int mt = 0; mt < 2; mt++)
                #pragma unroll
                for (int r = 0; r < 4; r++) {
                    float v = fmaxf(acc2[mt][nt][r], 0.f) * maskf[mt * 4 + r];
                    m = fmaxf(m, v);
                }
            m = fmaxf(m, __shfl_xor(m, 16));
            m = fmaxf(m, __shfl_xor(m, 32));
            fm[nt] = m;
        }
        float fv = (q == 0) ? fm[0] : (q == 1) ? fm[1] : (q == 2) ? fm[2] : fm[3];
        ft[(wave * 4 + it) * 72 + lane] = (half_t)fv;   // row = 4w+it, col = lane

        int lm = 0;
        #pragma unroll
        for (int j = 0; j < 8; j++) lm |= (maskf[j] != 0.f);
        unsigned long long bal = __ballot(lm);
        if (lane == 0) validb[wave * 4 + it] = bal ? 1 : 0;

        // ---- commit prefetch: convert to half frags (f32 temps die) ----
        if (it < 3) {
            if (lane >= 32) maskb[wave][(it + 1) & 1][lane - 32] = mnext;
            #pragma unroll
            for (int mt = 0; mt < 2; mt++) {
                half8 v;
                #pragma unroll
                for (int j = 0; j < 8; j++) v[j] = (half_t)0.f;
                if (q == 0) {
                    #pragma unroll
                    for (int j = 0; j < 8; j++) v[j] = (half_t)xn[mt][j];
                } else if (q == 1) {
                    v[0] = (half_t)xn[mt][0];
                }
                xa[mt] = v;
            }
        }
    }

    // =============== out-MLP stage (M=32 rows per block) ===============
    // 8 waves <-> 8 tiles: wave w owns (mt_o = w>>2, nt1 = w&3) for out1,
    // cols nt1 and nt1+4 for out2. B-frags straight from global (L2).
    const int mt_o = wave >> 2, nt1 = wave & 3;
    float bb1 = b1[nt1 * 16 + l15];
    half8 bw1[2];
    #pragma unroll
    for (int ks = 0; ks < 2; ks++)
        #pragma unroll
        for (int j = 0; j < 8; j++)
            bw1[ks][j] = (half_t)w1[(ks * 32 + q * 8 + j) * 64 + nt1 * 16 + l15];

    float bb2[2];
    half8 bw2[2][2];   // [ks][t]
    #pragma unroll
    for (int t = 0; t < 2; t++) {
        int c = (nt1 + 4 * t) * 16 + l15;
        bb2[t] = b2[c];
        #pragma unroll
        for (int ks = 0; ks < 2; ks++)
            #pragma unroll
            for (int j = 0; j < 8; j++)
                bw2[ks][t][j] = (half_t)w2[(ks * 32 + q * 8 + j) * 128 + c];
    }

    __syncthreads();   // ft + validb complete

    // out1: wave w computes rows mt_o*16.., cols nt1*16..
    f32x4 o1;
    #pragma unroll
    for (int r = 0; r < 4; r++) o1[r] = bb1;
    #pragma unroll
    for (int ks = 0; ks < 2; ks++) {
        half8 a = ld8(&ft[(mt_o * 16 + l15) * 72 + ks * 32 + q * 8]);
        o1 = MFMA(a, bw1[ks], o1);
    }
    #pragma unroll
    for (int r = 0; r < 4; r++) {
        float v = fmaxf(o1[r], 0.f);
        qt[(mt_o * 16 + q * 4 + r) * 72 + nt1 * 16 + l15] = (half_t)v;
    }

    __syncthreads();   // qt complete

    // out2: wave w computes rows mt_o*16.., cols nt1*16 and (nt1+4)*16
    f32x4 o2[2];
    #pragma unroll
    for (int t = 0; t < 2; t++)
        #pragma unroll
        for (int r = 0; r < 4; r++) o2[t][r] = bb2[t];
    #pragma unroll
    for (int ks = 0; ks < 2; ks++) {
        half8 a = ld8(&qt[(mt_o * 16 + l15) * 72 + ks * 32 + q * 8]);
        o2[0] = MFMA(a, bw2[ks][0], o2[0]);
        o2[1] = MFMA(a, bw2[ks][1], o2[1]);
    }
    #pragma unroll
    for (int r = 0; r < 4; r++) {
        int row = mt_o * 16 + q * 4 + r;
        float vr = validb[row] ? 1.f : 0.f;
        long rowg = (long)(blockIdx.x * 32 + row);
        out[rowg * 128 + (nt1 + 0) * 16 + l15] = o2[0][r] * vr;
        out[rowg * 128 + (nt1 + 4) * 16 + l15] = o2[1][r] * vr;
    }
}

extern "C" void kernel_launch(void* const* d_in, const int* in_sizes, int n_in,
                              void* d_out, int out_size, void* d_ws, size_t ws_size,
                              hipStream_t stream) {
    (void)in_sizes; (void)n_in; (void)out_size; (void)d_ws; (void)ws_size;
    k_fused<<<dim3(NPOLY / 32), dim3(512), 0, stream>>>(
        (const float*)d_in[0], (const int*)d_in[1],
        (const float*)d_in[2],  (const float*)d_in[3],  (const float*)d_in[4],
        (const float*)d_in[5],  (const float*)d_in[6],  (const float*)d_in[7],
        (const float*)d_in[8],  (const float*)d_in[9],  (const float*)d_in[10],
        (const float*)d_in[11], (const float*)d_in[12], (const float*)d_in[13],
        (const float*)d_in[14], (const float*)d_in[15], (const float*)d_in[16],
        (const float*)d_in[17], (const float*)d_in[18], (const float*)d_in[19],
        (const float*)d_in[20], (const float*)d_in[21],
        (const float*)d_in[22], (const float*)d_in[23],
        (float*)d_out);
}

// Round 13
// 149.905 us; speedup vs baseline: 1.0527x; 1.0318x over previous
//
#include <hip/hip_runtime.h>

typedef _Float16 half_t;
typedef __attribute__((ext_vector_type(4))) _Float16 half4;   // 2 VGPRs
typedef __attribute__((ext_vector_type(8))) _Float16 half8;   // MFMA A/B frag (4 VGPRs)
typedef __attribute__((ext_vector_type(4))) float f32x4;      // MFMA C/D frag

#define NPOLY 16384   // B*N
#define PPTS  32
#define CIN   9

__device__ __forceinline__ half8 ld8(const half_t* p){
    return *reinterpret_cast<const half8*>(p);
}
__device__ __forceinline__ f32x4 MFMA(half8 a, half8 b, f32x4 c){
    return __builtin_amdgcn_mfma_f32_16x16x32_f16(a, b, c, 0, 0, 0);
}
// Fragment layouts (measured, learn_hip m89/m120; dtype-independent):
//   A[m][k]: m = lane&15 (+16*mt), k = (lane>>4)*8 + j (+32*ks)
//   B[k][n]: n = lane&15 (+16*nt), k = (lane>>4)*8 + j (+32*ks)
//   C/D[row][col]: col = lane&15 (+16*nt), row = (lane>>4)*4 + r (+16*mt)

// =====================================================================
// LESSONS: (r1) d_ws re-poisoned each iter -> never read it.
// (r2/r5/r9/r11/r12) VGPR cap 128 at this shape; [feat][point] read
// path spills NO MATTER the source structure -> abandoned. (r3)
// occupancy: no effect. (r4) rolled loop: best 43.6us @ VGPR=116.
// (r6) stagger/setprio: regression. (r7/r8) tr_b16: abandoned.
// THIS ROUND: swap l1's operands: G = W1^T (A) x f (B).
//  - B-frag = f[point=l15][feat=q*8+j] = r4's EXISTING b128 reads.
//  - D = [feat_out][point]: lane quad = 4 consecutive feats at point
//    l15 -> ONE half4 store into the same [point][feat] buffer ->
//    l1 stores 32 b16 -> 8 b64, conflict-free; l2 reads unchanged.
//  - A-frag staging expression IDENTICAL (W[k*64+col]*sA).
//  - bias sC1 now feat_out-indexed: 16 regs; offset by xa-half8
//    conversion (-8 regs). Est peak ~120 < 128.
// pre & l2 stay unswapped (point-major D needed for cheap pooled max).
// Block = 512 thr (8 waves) = 32 polylines; grid 512 = 2 blocks/CU.
// =====================================================================
__global__ __launch_bounds__(512, 2) void k_fused(
    const float* __restrict__ px,        // [NPOLY][32][9]
    const int*   __restrict__ pmask,     // [NPOLY][32]
    const float* __restrict__ w_pre, const float* __restrict__ b_pre,
    const float* __restrict__ g_pre, const float* __restrict__ be_pre,
    const float* __restrict__ rm_pre, const float* __restrict__ rv_pre,
    const float* __restrict__ w_m1, const float* __restrict__ b_m1,
    const float* __restrict__ g_m1, const float* __restrict__ be_m1,
    const float* __restrict__ rm_m1, const float* __restrict__ rv_m1,
    const float* __restrict__ w_m2, const float* __restrict__ b_m2,
    const float* __restrict__ g_m2, const float* __restrict__ be_m2,
    const float* __restrict__ rm_m2, const float* __restrict__ rv_m2,
    const float* __restrict__ w1, const float* __restrict__ b1,
    const float* __restrict__ w2, const float* __restrict__ b2,
    float* __restrict__ out)
{
    // encoder weight frags (f16, BN-scaled): pre 0..3, m1 4..19, m2 20..27
    __shared__ __align__(16) half_t lds_w[28 * 512];   // 28 KB
    __shared__ __align__(16) half_t fg[8][32 * 72];    // 36 KB per-wave f/g [point][feat]
    __shared__ __align__(16) half_t pooledb[8][64];    // 1 KB
    __shared__ __align__(16) half_t ft[32 * 72];       // 4.5 KB feat A-tile (32 rows)
    __shared__ __align__(16) half_t qt[32 * 72];       // 4.5 KB out1 A-tile
    __shared__ int maskb[8][2][32];                    // 2 KB (double-buffered)
    __shared__ int validb[32];

    const int tid  = threadIdx.x;
    const int wave = tid >> 6, lane = tid & 63, l15 = lane & 15, q = lane >> 4;

    // ---- stage encoder weights, fp32 -> f16, folding BN scale sA ----
    // NOTE: for l1 these frags are interpreted as A = W1^T tiles
    // (A[m=16ot+l15][k=32ks+q*8+j] = W[k*64+col] -- same expression).
    #pragma unroll 1
    for (int s = tid; s < 28 * 64; s += 512) {
        int frag = s >> 6, ln = s & 63;
        const float *W, *G, *RV; int K, ks, nt;
        if (frag < 4)       { W = w_pre; G = g_pre; RV = rv_pre; K = CIN; ks = 0; nt = frag; }
        else if (frag < 20) { W = w_m1;  G = g_m1;  RV = rv_m1;  K = 128; int f = frag - 4;  ks = f >> 2; nt = f & 3; }
        else                { W = w_m2;  G = g_m2;  RV = rv_m2;  K = 64;  int f = frag - 20; ks = f >> 2; nt = f & 3; }
        int col = nt * 16 + (ln & 15);
        int kb  = ks * 32 + ((ln >> 4) << 3);
        float sA = G[col] * rsqrtf(RV[col] + 1e-5f);
        half_t* dst = &lds_w[s * 8];
        #pragma unroll
        for (int j = 0; j < 8; j++) {
            int k  = kb + j;
            int ka = (k < K) ? k : 0;
            float v = W[ka * 64 + col] * sA;
            dst[j] = (k < K) ? (half_t)v : (half_t)0.f;
        }
    }

    // ---- per-lane BN bias consts ----
    // pre/l2 (unswapped): indexed h = nt*16 + l15 (4 regs each).
    // l1 (swapped): indexed feat_out = 16ot + q*4 + r (f32x4 per ot).
    float sC0[4], sC2[4];
    f32x4 sC1v[4];
    #pragma unroll
    for (int nt = 0; nt < 4; nt++) {
        int h = nt * 16 + l15; float a;
        a = g_pre[h] * rsqrtf(rv_pre[h] + 1e-5f); sC0[nt] = (b_pre[h] - rm_pre[h]) * a + be_pre[h];
        a = g_m2[h]  * rsqrtf(rv_m2[h]  + 1e-5f); sC2[nt] = (b_m2[h]  - rm_m2[h])  * a + be_m2[h];
    }
    #pragma unroll
    for (int ot = 0; ot < 4; ot++)
        #pragma unroll
        for (int r = 0; r < 4; r++) {
            int h = ot * 16 + q * 4 + r;
            float a = g_m1[h] * rsqrtf(rv_m1[h] + 1e-5f);
            sC1v[ot][r] = (b_m1[h] - rm_m1[h]) * a + be_m1[h];
        }

    const int nbase = blockIdx.x * 32 + wave * 4;
    half_t* const fgw = &fg[wave][0];
    const half_t* const lwb = lds_w + lane * 8;
    half_t* const pbw = &pooledb[wave][0];

    // ---- iter-0 x: load AND convert to half8 immediately (-8 regs) ----
    half8 xa[2];
    {
        float x0[2][8];
        #pragma unroll
        for (int mt = 0; mt < 2; mt++) {
            const float* src = px + ((long)nbase * PPTS + l15 + 16 * mt) * CIN;
            if (q == 0) {
                #pragma unroll
                for (int j = 0; j < 8; j++) x0[mt][j] = src[j];
            } else if (q == 1) {
                x0[mt][0] = src[8];
            }
        }
        #pragma unroll
        for (int mt = 0; mt < 2; mt++) {
            half8 v;
            #pragma unroll
            for (int j = 0; j < 8; j++) v[j] = (half_t)0.f;
            if (q == 0) {
                #pragma unroll
                for (int j = 0; j < 8; j++) v[j] = (half_t)x0[mt][j];
            } else if (q == 1) {
                v[0] = (half_t)x0[mt][0];
            }
            xa[mt] = v;
        }
    }
    if (lane >= 32) maskb[wave][0][lane - 32] = pmask[nbase * PPTS + (lane - 32)];

    __syncthreads();   // weights staged

    // pre-layer B-frags reused every iteration: hoist to registers
    half8 preb[4];
    #pragma unroll
    for (int nt = 0; nt < 4; nt++) preb[nt] = ld8(lwb + nt * 512);

    // ---- main loop: rolled (r4 lesson) ----
    #pragma unroll 1
    for (int it = 0; it < 4; ++it) {
        const int n = nbase + it;

        // ---- issue next-iteration prefetch loads (consumed at iter end) ----
        float xn[2][8]; int mnext = 0;
        if (it < 3) {
            #pragma unroll
            for (int mt = 0; mt < 2; mt++) {
                const float* src = px + ((long)(n + 1) * PPTS + l15 + 16 * mt) * CIN;
                if (q == 0) {
                    #pragma unroll
                    for (int j = 0; j < 8; j++) xn[mt][j] = src[j];
                } else if (q == 1) {
                    xn[mt][0] = src[8];
                }
            }
            if (lane >= 32) mnext = pmask[(n + 1) * PPTS + (lane - 32)];
        }

        // ---- pre layer (unswapped): acc init = sC0 (BN bias) ----
        f32x4 acc[2][4];
        #pragma unroll
        for (int mt = 0; mt < 2; mt++)
            #pragma unroll
            for (int nt = 0; nt < 4; nt++)
                #pragma unroll
                for (int r = 0; r < 4; r++) acc[mt][nt][r] = sC0[nt];

        #pragma unroll
        for (int nt = 0; nt < 4; nt++) {
            acc[0][nt] = MFMA(xa[0], preb[nt], acc[0][nt]);
            acc[1][nt] = MFMA(xa[1], preb[nt], acc[1][nt]);
        }

        float maskf[8];
        #pragma unroll
        for (int mt = 0; mt < 2; mt++)
            #pragma unroll
            for (int r = 0; r < 4; r++)
                maskf[mt * 4 + r] = maskb[wave][it & 1][mt * 16 + q * 4 + r] ? 1.f : 0.f;

        // ReLU+mask, write masked f [point][feat], track pooled max
        float pm[4];
        #pragma unroll
        for (int nt = 0; nt < 4; nt++) {
            float m = 0.f;
            #pragma unroll
            for (int mt = 0; mt < 2; mt++)
                #pragma unroll
                for (int r = 0; r < 4; r++) {
                    float v = fmaxf(acc[mt][nt][r], 0.f) * maskf[mt * 4 + r];
                    fgw[(mt * 16 + q * 4 + r) * 72 + nt * 16 + l15] = (half_t)v;
                    m = fmaxf(m, v);
                }
            m = fmaxf(m, __shfl_xor(m, 16));
            m = fmaxf(m, __shfl_xor(m, 32));
            pm[nt] = m;
        }
        {
            float pv = (q == 0) ? pm[0] : (q == 1) ? pm[1] : (q == 2) ? pm[2] : pm[3];
            pbw[lane] = (half_t)pv;   // col = q*16+l15 = lane
        }

        // ---- l1 SWAPPED: G = W1^T (A) x [f | pooled] (B), D=[feat][point] ----
        // acc1[ot][nt]: rows = feat_out 16ot+q*4+r, cols = point nt*16+l15
        f32x4 acc1[4][2];
        #pragma unroll
        for (int ot = 0; ot < 4; ot++)
            #pragma unroll
            for (int nt = 0; nt < 2; nt++)
                acc1[ot][nt] = sC1v[ot];

        half8 pa0 = ld8(pbw + q * 8);
        half8 pa1 = ld8(pbw + 32 + q * 8);
        #pragma unroll
        for (int ks = 0; ks < 2; ks++) {
            // B-frags = f[point][feat]: identical reads to r4's A-frags
            half8 b0 = ld8(fgw + l15 * 72 + ks * 32 + q * 8);
            half8 b1 = ld8(fgw + (l15 + 16) * 72 + ks * 32 + q * 8);
            #pragma unroll
            for (int ot = 0; ot < 4; ot++) {
                half8 wa = ld8(lwb + (4 + ks * 4 + ot) * 512);
                acc1[ot][0] = MFMA(wa, b0, acc1[ot][0]);
                acc1[ot][1] = MFMA(wa, b1, acc1[ot][1]);
            }
        }
        #pragma unroll
        for (int ks = 2; ks < 4; ks++) {
            half8 bp = (ks == 2) ? pa0 : pa1;   // pooled bcast over points
            #pragma unroll
            for (int ot = 0; ot < 4; ot++) {
                half8 wa = ld8(lwb + (4 + ks * 4 + ot) * 512);
                acc1[ot][0] = MFMA(wa, bp, acc1[ot][0]);
                acc1[ot][1] = MFMA(wa, bp, acc1[ot][1]);
            }
        }

        // ReLU -> packed half4 stores into [point][feat] (8 x ds_write_b64)
        #pragma unroll
        for (int ot = 0; ot < 4; ot++)
            #pragma unroll
            for (int nt = 0; nt < 2; nt++) {
                half4 h;
                h[0] = (half_t)fmaxf(acc1[ot][nt][0], 0.f);
                h[1] = (half_t)fmaxf(acc1[ot][nt][1], 0.f);
                h[2] = (half_t)fmaxf(acc1[ot][nt][2], 0.f);
                h[3] = (half_t)fmaxf(acc1[ot][nt][3], 0.f);
                *reinterpret_cast<half4*>(fgw + (nt * 16 + l15) * 72 + ot * 16 + q * 4) = h;
            }

        // ---- l2 (unswapped): (32x64) @ (64x64), acc init sC2 ----
        f32x4 acc2[2][4];
        #pragma unroll
        for (int mt = 0; mt < 2; mt++)
            #pragma unroll
            for (int nt = 0; nt < 4; nt++)
                #pragma unroll
                for (int r = 0; r < 4; r++) acc2[mt][nt][r] = sC2[nt];
        #pragma unroll
        for (int ks = 0; ks < 2; ks++) {
            half8 a0 = ld8(fgw + l15 * 72 + ks * 32 + q * 8);
            half8 a1 = ld8(fgw + (l15 + 16) * 72 + ks * 32 + q * 8);
            #pragma unroll
            for (int nt = 0; nt < 4; nt++) {
                half8 b = ld8(lwb + (20 + ks * 4 + nt) * 512);
                acc2[0][nt] = MFMA(a0, b, acc2[0][nt]);
                acc2[1][nt] = MFMA(a1, b, acc2[1][nt]);
            }
        }

        // ReLU+mask, masked max over points -> feat row into ft tile (f16)
        float fm[4];
        #pragma unroll
        for (int nt = 0; nt < 4; nt++) {
            float m = 0.f;
            #pragma unroll
            for (int mt = 0; mt < 2; mt++)
                #pragma unroll
                for (int r = 0; r < 4; r++) {
                    float v = fmaxf(acc2[mt][nt][r], 0.f) * maskf[mt * 4 + r];
                    m = fmaxf(m, v);
                }
            m = fmaxf(m, __shfl_xor(m, 16));
            m = fmaxf(m, __shfl_xor(m, 32));
            fm[nt] = m;
        }
        float fv = (q == 0) ? fm[0] : (q == 1) ? fm[1] : (q == 2) ? fm[2] : fm[3];
        ft[(wave * 4 + it) * 72 + lane] = (half_t)fv;   // row = 4w+it, col = lane

        int lm = 0;
        #pragma unroll
        for (int j = 0; j < 8; j++) lm |= (maskf[j] != 0.f);
        unsigned long long bal = __ballot(lm);
        if (lane == 0) validb[wave * 4 + it] = bal ? 1 : 0;

        // ---- commit prefetch: convert to half frags (f32 temps die) ----
        if (it < 3) {
            if (lane >= 32) maskb[wave][(it + 1) & 1][lane - 32] = mnext;
            #pragma unroll
            for (int mt = 0; mt < 2; mt++) {
                half8 v;
                #pragma unroll
                for (int j = 0; j < 8; j++) v[j] = (half_t)0.f;
                if (q == 0) {
                    #pragma unroll
                    for (int j = 0; j < 8; j++) v[j] = (half_t)xn[mt][j];
                } else if (q == 1) {
                    v[0] = (half_t)xn[mt][0];
                }
                xa[mt] = v;
            }
        }
    }

    // =============== out-MLP stage (M=32 rows per block) ===============
    // 8 waves <-> 8 tiles: wave w owns (mt_o = w>>2, nt1 = w&3) for out1,
    // cols nt1 and nt1+4 for out2. B-frags straight from global (L2).
    const int mt_o = wave >> 2, nt1 = wave & 3;
    float bb1 = b1[nt1 * 16 + l15];
    half8 bw1[2];
    #pragma unroll
    for (int ks = 0; ks < 2; ks++)
        #pragma unroll
        for (int j = 0; j < 8; j++)
            bw1[ks][j] = (half_t)w1[(ks * 32 + q * 8 + j) * 64 + nt1 * 16 + l15];

    float bb2[2];
    half8 bw2[2][2];   // [ks][t]
    #pragma unroll
    for (int t = 0; t < 2; t++) {
        int c = (nt1 + 4 * t) * 16 + l15;
        bb2[t] = b2[c];
        #pragma unroll
        for (int ks = 0; ks < 2; ks++)
            #pragma unroll
            for (int j = 0; j < 8; j++)
                bw2[ks][t][j] = (half_t)w2[(ks * 32 + q * 8 + j) * 128 + c];
    }

    __syncthreads();   // ft + validb complete

    // out1: wave w computes rows mt_o*16.., cols nt1*16..
    f32x4 o1;
    #pragma unroll
    for (int r = 0; r < 4; r++) o1[r] = bb1;
    #pragma unroll
    for (int ks = 0; ks < 2; ks++) {
        half8 a = ld8(&ft[(mt_o * 16 + l15) * 72 + ks * 32 + q * 8]);
        o1 = MFMA(a, bw1[ks], o1);
    }
    #pragma unroll
    for (int r = 0; r < 4; r++) {
        float v = fmaxf(o1[r], 0.f);
        qt[(mt_o * 16 + q * 4 + r) * 72 + nt1 * 16 + l15] = (half_t)v;
    }

    __syncthreads();   // qt complete

    // out2: wave w computes rows mt_o*16.., cols nt1*16 and (nt1+4)*16
    f32x4 o2[2];
    #pragma unroll
    for (int t = 0; t < 2; t++)
        #pragma unroll
        for (int r = 0; r < 4; r++) o2[t][r] = bb2[t];
    #pragma unroll
    for (int ks = 0; ks < 2; ks++) {
        half8 a = ld8(&qt[(mt_o * 16 + l15) * 72 + ks * 32 + q * 8]);
        o2[0] = MFMA(a, bw2[ks][0], o2[0]);
        o2[1] = MFMA(a, bw2[ks][1], o2[1]);
    }
    #pragma unroll
    for (int r = 0; r < 4; r++) {
        int row = mt_o * 16 + q * 4 + r;
        float vr = validb[row] ? 1.f : 0.f;
        long rowg = (long)(blockIdx.x * 32 + row);
        out[rowg * 128 + (nt1 + 0) * 16 + l15] = o2[0][r] * vr;
        out[rowg * 128 + (nt1 + 4) * 16 + l15] = o2[1][r] * vr;
    }
}

extern "C" void kernel_launch(void* const* d_in, const int* in_sizes, int n_in,
                              void* d_out, int out_size, void* d_ws, size_t ws_size,
                              hipStream_t stream) {
    (void)in_sizes; (void)n_in; (void)out_size; (void)d_ws; (void)ws_size;
    k_fused<<<dim3(NPOLY / 32), dim3(512), 0, stream>>>(
        (const float*)d_in[0], (const int*)d_in[1],
        (const float*)d_in[2],  (const float*)d_in[3],  (const float*)d_in[4],
        (const float*)d_in[5],  (const float*)d_in[6],  (const float*)d_in[7],
        (const float*)d_in[8],  (const float*)d_in[9],  (const float*)d_in[10],
        (const float*)d_in[11], (const float*)d_in[12], (const float*)d_in[13],
        (const float*)d_in[14], (const float*)d_in[15], (const float*)d_in[16],
        (const float*)d_in[17], (const float*)d_in[18], (const float*)d_in[19],
        (const float*)d_in[20], (const float*)d_in[21],
        (const float*)d_in[22], (const float*)d_in[23],
        (float*)d_out);
}